// Round 1
// baseline (278.471 us; speedup 1.0000x reference)
//
#include <hip/hip_runtime.h>
#include <hip/hip_bf16.h>
#include <stdint.h>

#define NN    4096
#define INF_  256
#define HEADS 4
#define HID   64
#define OUTC  256
#define NEG   0.2f

#define BI     32
#define BJ     64
#define JSPLIT 4
#define WROW   276   // f32 stride per i-row of wlds: [i]*276 + h*68 + jj  (conflict-free b128 writes)

// ---- float <-> order-preserving uint encoding (for atomicMax on f32) ----
__device__ __forceinline__ uint32_t ford(float x){
  uint32_t u = __float_as_uint(x);
  return (u & 0x80000000u) ? ~u : (u | 0x80000000u);
}
__device__ __forceinline__ float funord(uint32_t e){
  uint32_t u = (e & 0x80000000u) ? (e & 0x7fffffffu) : ~e;
  return __uint_as_float(u);
}

// ---- W[256][256] -> Wt[k][c] = W[c][k] ----
__global__ void k_transposeW(const float* __restrict__ W, float* __restrict__ Wt){
  __shared__ float tile[32][33];
  int bx = blockIdx.x, by = blockIdx.y;
  int tx = threadIdx.x, ty = threadIdx.y;   // (32,8)
  #pragma unroll
  for (int q = 0; q < 4; q++)
    tile[ty + 8*q][tx] = W[(by*32 + ty + 8*q)*INF_ + bx*32 + tx];
  __syncthreads();
  #pragma unroll
  for (int q = 0; q < 4; q++)
    Wt[(bx*32 + ty + 8*q)*OUTC + by*32 + tx] = tile[tx][ty + 8*q];
}

// ---- detect adjacency element layout ----
// scans first NN*NN/4 words (== first 16.7MB, valid under every candidate layout)
// flag bit0: saw word >1 that's not 1.0f pattern  -> byte layout
// flag bit1: saw 0x3F800000                       -> f32 layout
// neither                                         -> int32 layout
__global__ void k_detect(const uint32_t* __restrict__ a, int nwords, int* __restrict__ flag){
  int idx = blockIdx.x*256 + threadIdx.x;
  int stride = gridDim.x*256;
  int f = 0;
  for (int i = idx; i < nwords; i += stride){
    uint32_t v = a[i];
    if (v > 1u) f |= (v == 0x3F800000u) ? 2 : 1;
  }
  if (f) atomicOr(flag, f);
}

// ---- g = h @ W^T  (64x64 tile per block, head == col-tile), plus sl/sr scores + srmax ----
__launch_bounds__(256)
__global__ void k_gemm(const float* __restrict__ hmat, const float* __restrict__ Wt,
                       const float* __restrict__ aw,
                       float* __restrict__ g, float* __restrict__ sl, float* __restrict__ sr,
                       uint32_t* __restrict__ srmax){
  __shared__ float hsT[64][68];   // [k][row]
  __shared__ float wsT[64][68];   // [k][col]
  __shared__ float smax_l[16];
  int t  = threadIdx.x;
  int tx = t & 15, ty = t >> 4;
  int r0 = blockIdx.x * 64;
  int cb = blockIdx.y;            // head
  int c0 = cb * 64;
  float acc[4][4] = {};

  for (int k0 = 0; k0 < INF_; k0 += 64){
    int row = t >> 2, kc = (t & 3) * 16;   // h-tile transpose-on-load
    #pragma unroll
    for (int u = 0; u < 4; u++){
      float4 v = *(const float4*)&hmat[(r0 + row)*INF_ + k0 + kc + 4*u];
      hsT[kc + 4*u + 0][row] = v.x;
      hsT[kc + 4*u + 1][row] = v.y;
      hsT[kc + 4*u + 2][row] = v.z;
      hsT[kc + 4*u + 3][row] = v.w;
    }
    int kk = t >> 2, c4 = (t & 3) * 16;
    #pragma unroll
    for (int u = 0; u < 4; u++)
      *(float4*)&wsT[kk][c4 + 4*u] = *(const float4*)&Wt[(k0 + kk)*OUTC + c0 + c4 + 4*u];
    __syncthreads();
    #pragma unroll 8
    for (int k = 0; k < 64; k++){
      float4 hv = *(const float4*)&hsT[k][ty*4];
      float4 wv = *(const float4*)&wsT[k][tx*4];
      float ha[4] = {hv.x, hv.y, hv.z, hv.w};
      float wa[4] = {wv.x, wv.y, wv.z, wv.w};
      #pragma unroll
      for (int a_ = 0; a_ < 4; a_++)
        #pragma unroll
        for (int b_ = 0; b_ < 4; b_++)
          acc[a_][b_] = fmaf(ha[a_], wa[b_], acc[a_][b_]);
    }
    __syncthreads();
  }

  float alv[4], arv[4];
  #pragma unroll
  for (int j = 0; j < 4; j++){ alv[j] = aw[tx*4 + j]; arv[j] = aw[64 + tx*4 + j]; }
  float rmax = -3.4e38f;
  #pragma unroll
  for (int qi = 0; qi < 4; qi++){
    int r = r0 + ty*4 + qi;
    *(float4*)&g[(size_t)r*OUTC + c0 + tx*4] =
        make_float4(acc[qi][0], acc[qi][1], acc[qi][2], acc[qi][3]);
    float slp = 0.f, srp = 0.f;
    #pragma unroll
    for (int j = 0; j < 4; j++){
      slp = fmaf(acc[qi][j], alv[j], slp);
      srp = fmaf(acc[qi][j], arv[j], srp);
    }
    #pragma unroll
    for (int m = 1; m < 16; m <<= 1){
      slp += __shfl_xor(slp, m, 64);
      srp += __shfl_xor(srp, m, 64);
    }
    if (tx == 0){
      sl[(size_t)r*4 + cb] = slp;
      sr[(size_t)r*4 + cb] = srp;
      rmax = fmaxf(rmax, srp);
    }
  }
  if (tx == 0) smax_l[ty] = rmax;
  __syncthreads();
  if (t == 0){
    float m = smax_l[0];
    #pragma unroll
    for (int i = 1; i < 16; i++) m = fmaxf(m, smax_l[i]);
    atomicMax(srmax + cb, ford(m));
  }
}

// ---- fused masked-softmax attention: num/den partials over a j-range ----
__launch_bounds__(256)
__global__ void k_attn(const float* __restrict__ g, const float* __restrict__ sl,
                       const float* __restrict__ sr, const uint32_t* __restrict__ srmax,
                       const uint8_t* __restrict__ adjb, const int* __restrict__ flag,
                       float* __restrict__ num, float* __restrict__ den){
  __shared__ float wlds[BI * WROW];
  __shared__ float srs[BJ * 5];
  int t  = threadIdx.x;
  int i0 = blockIdx.x * BI;
  int js = blockIdx.y;
  int jbase0 = js * (NN / JSPLIT);
  int ai = t >> 3, as = t & 7;     // phase A identity
  int h  = t >> 6, lane = t & 63;  // phase B identity
  int lay = *flag;

  float4 sl4 = *(const float4*)&sl[(size_t)(i0 + ai)*4];
  float slv[4] = {sl4.x, sl4.y, sl4.z, sl4.w};
  float msh[4];
  #pragma unroll
  for (int hh = 0; hh < 4; hh++){
    float x = slv[hh] + funord(srmax[hh]);
    msh[hh] = x >= 0.f ? x : NEG * x;
  }
  float denp[4] = {0.f, 0.f, 0.f, 0.f};
  float acc[BI];
  #pragma unroll
  for (int i = 0; i < BI; i++) acc[i] = 0.f;

  for (int step = 0; step < (NN / JSPLIT) / BJ; step++){
    int j0 = jbase0 + step * BJ;
    __syncthreads();                       // protect wlds/srs from prior phase B
    if (t < 64){
      float4 v = *(const float4*)&sr[(size_t)(j0 + t)*4];
      srs[t*5 + 0] = v.x; srs[t*5 + 1] = v.y; srs[t*5 + 2] = v.z; srs[t*5 + 3] = v.w;
    }
    __syncthreads();

    // ---- phase A: weights for (ai, jj = as*8..+7, all heads) ----
    size_t abase = (size_t)(i0 + ai)*NN + j0 + as*8;
    uint32_t bits;
    if (lay & 1){                      // byte layout
      uint2 v = *(const uint2*)(adjb + abase);
      uint32_t b0 = v.x, b1 = v.y;
      bits = ((b0 & 0xffu)      ? 1u   : 0u) | ((b0 & 0xff00u)     ? 2u   : 0u)
           | ((b0 & 0xff0000u)  ? 4u   : 0u) | ((b0 & 0xff000000u) ? 8u   : 0u)
           | ((b1 & 0xffu)      ? 16u  : 0u) | ((b1 & 0xff00u)     ? 32u  : 0u)
           | ((b1 & 0xff0000u)  ? 64u  : 0u) | ((b1 & 0xff000000u) ? 128u : 0u);
    } else if (lay & 2){               // f32 layout
      const float* af = (const float*)adjb;
      float4 v0 = *(const float4*)(af + abase);
      float4 v1 = *(const float4*)(af + abase + 4);
      bits = (v0.x != 0.f ? 1u : 0u) | (v0.y != 0.f ? 2u : 0u)
           | (v0.z != 0.f ? 4u : 0u) | (v0.w != 0.f ? 8u : 0u)
           | (v1.x != 0.f ? 16u : 0u) | (v1.y != 0.f ? 32u : 0u)
           | (v1.z != 0.f ? 64u : 0u) | (v1.w != 0.f ? 128u : 0u);
    } else {                           // int32 layout
      const int* ap = (const int*)adjb;
      int4 v0 = *(const int4*)(ap + abase);
      int4 v1 = *(const int4*)(ap + abase + 4);
      bits = (v0.x ? 1u : 0u) | (v0.y ? 2u : 0u) | (v0.z ? 4u : 0u) | (v0.w ? 8u : 0u)
           | (v1.x ? 16u : 0u) | (v1.y ? 32u : 0u) | (v1.z ? 64u : 0u) | (v1.w ? 128u : 0u);
    }
    #pragma unroll
    for (int hh = 0; hh < 4; hh++){
      float w[8];
      #pragma unroll
      for (int q = 0; q < 8; q++){
        int jj = as*8 + q;
        float x = slv[hh] + srs[jj*5 + hh];
        float e = x >= 0.f ? x : NEG * x;
        float wv = ((bits >> q) & 1u) ? __expf(e - msh[hh]) : 0.f;
        w[q] = wv;
        denp[hh] += wv;
      }
      float* wp = &wlds[ai*WROW + hh*68 + as*8];
      *(float4*)wp       = make_float4(w[0], w[1], w[2], w[3]);
      *(float4*)(wp + 4) = make_float4(w[4], w[5], w[6], w[7]);
    }
    __syncthreads();

    // ---- phase B: wave h accumulates its head's 64 cols over these 64 j ----
    #pragma unroll 1
    for (int jc = 0; jc < 8; jc++){
      float gv[8];
      #pragma unroll
      for (int q = 0; q < 8; q++)
        gv[q] = g[(size_t)(j0 + jc*8 + q)*OUTC + h*HID + lane];
      #pragma unroll
      for (int i = 0; i < BI; i++){
        const float* wp = &wlds[i*WROW + h*68 + jc*8];
        float4 wa = *(const float4*)wp;
        float4 wb = *(const float4*)(wp + 4);
        float a = acc[i];
        a = fmaf(wa.x, gv[0], a); a = fmaf(wa.y, gv[1], a);
        a = fmaf(wa.z, gv[2], a); a = fmaf(wa.w, gv[3], a);
        a = fmaf(wb.x, gv[4], a); a = fmaf(wb.y, gv[5], a);
        a = fmaf(wb.z, gv[6], a); a = fmaf(wb.w, gv[7], a);
        acc[i] = a;
      }
    }
  }

  #pragma unroll
  for (int i = 0; i < BI; i++)
    num[((size_t)js*NN + i0 + i)*OUTC + h*HID + lane] = acc[i];

  #pragma unroll
  for (int hh = 0; hh < 4; hh++){
    denp[hh] += __shfl_xor(denp[hh], 1, 64);
    denp[hh] += __shfl_xor(denp[hh], 2, 64);
    denp[hh] += __shfl_xor(denp[hh], 4, 64);
  }
  if (as == 0)
    *(float4*)&den[((size_t)js*NN + i0 + ai)*4] =
        make_float4(denp[0], denp[1], denp[2], denp[3]);
}

// ---- combine partials: out = sum(num)/sum(den) ----
__global__ void k_comb(const float* __restrict__ num, const float* __restrict__ den,
                       float* __restrict__ out){
  int r = blockIdx.x, t = threadIdx.x;
  float s = 0.f, d = 0.f;
  #pragma unroll
  for (int js = 0; js < JSPLIT; js++) s += num[((size_t)js*NN + r)*OUTC + t];
  #pragma unroll
  for (int js = 0; js < JSPLIT; js++) d += den[((size_t)js*NN + r)*4 + (t >> 6)];
  out[(size_t)r*OUTC + t] = s / d;
}

extern "C" void kernel_launch(void* const* d_in, const int* in_sizes, int n_in,
                              void* d_out, int out_size, void* d_ws, size_t ws_size,
                              hipStream_t stream){
  const float*   hmat = (const float*)d_in[0];
  const uint8_t* adj  = (const uint8_t*)d_in[1];
  const float*   W    = (const float*)d_in[2];
  const float*   aw   = (const float*)d_in[3];
  float* out = (float*)d_out;
  char*  ws  = (char*)d_ws;

  // ws layout (bytes): total ~20.6 MB
  int*      flag  = (int*)(ws);
  uint32_t* srmax = (uint32_t*)(ws + 64);
  float* sl  = (float*)(ws + 1024);
  float* sr  = (float*)(ws + 1024 + 65536);
  float* Wt  = (float*)(ws + 1024 + 131072);
  float* g   = (float*)(ws + 1024 + 131072 + 262144);
  float* num = (float*)(ws + 4588544);
  float* den = (float*)(ws + 21365760);

  hipMemsetAsync(ws, 0, 1024, stream);   // flag + srmax init
  hipLaunchKernelGGL(k_transposeW, dim3(8, 8), dim3(32, 8), 0, stream, W, Wt);
  hipLaunchKernelGGL(k_detect, dim3(1024), dim3(256), 0, stream,
                     (const uint32_t*)adj, NN*NN/4, flag);
  hipLaunchKernelGGL(k_gemm, dim3(64, 4), dim3(256), 0, stream,
                     hmat, Wt, aw, g, sl, sr, srmax);
  hipLaunchKernelGGL(k_attn, dim3(128, JSPLIT), dim3(256), 0, stream,
                     g, sl, sr, srmax, adj, flag, num, den);
  hipLaunchKernelGGL(k_comb, dim3(4096), dim3(256), 0, stream, num, den, out);
}

// Round 2
// 90.098 us; speedup vs baseline: 3.0907x; 3.0907x over previous
//
#include <hip/hip_runtime.h>
#include <hip/hip_bf16.h>
#include <stdint.h>

#define NN    4096
#define INF_  256
#define HEADS 4
#define HID   64
#define OUTC  256
#define NEG   0.2f
#define L2E   1.44269504f

#define BI     64
#define JSPLIT 8

typedef short bf16x8 __attribute__((ext_vector_type(8)));
typedef float f32x4  __attribute__((ext_vector_type(4)));

// ---- float <-> order-preserving uint encoding (for atomicMax on f32) ----
__device__ __forceinline__ uint32_t ford(float x){
  uint32_t u = __float_as_uint(x);
  return (u & 0x80000000u) ? ~u : (u | 0x80000000u);
}
__device__ __forceinline__ float funord(uint32_t e){
  uint32_t u = (e & 0x80000000u) ? (e & 0x7fffffffu) : ~e;
  return __uint_as_float(u);
}
__device__ __forceinline__ ushort bf16u(float f){
  __hip_bfloat16 b = __float2bfloat16(f);
  return *reinterpret_cast<ushort*>(&b);
}

// ---- g = h @ W^T per head-tile; emits gT (bf16, [c][j] transposed), slT2/srT2
//      (log2e-scaled scores) and per-head scaled srmax ----
__launch_bounds__(256)
__global__ void k_gemm(const float* __restrict__ hmat, const float* __restrict__ W,
                       const float* __restrict__ aw,
                       short* __restrict__ gT, float* __restrict__ slT2,
                       float* __restrict__ srT2, uint32_t* __restrict__ srmax2){
  __shared__ float hsT[64][68];   // [k][row]
  __shared__ float wsT[64][68];   // [k][col]
  __shared__ float smax_l[16];
  int t  = threadIdx.x;
  int tx = t & 15, ty = t >> 4;
  int r0 = blockIdx.x * 64;
  int cb = blockIdx.y;            // head
  int c0 = cb * 64;
  float acc[4][4] = {};

  for (int k0 = 0; k0 < INF_; k0 += 64){
    int row = t >> 2, kc = (t & 3) * 16;   // transpose-on-load (h tile)
    #pragma unroll
    for (int u = 0; u < 4; u++){
      float4 v = *(const float4*)&hmat[(r0 + row)*INF_ + k0 + kc + 4*u];
      hsT[kc + 4*u + 0][row] = v.x;
      hsT[kc + 4*u + 1][row] = v.y;
      hsT[kc + 4*u + 2][row] = v.z;
      hsT[kc + 4*u + 3][row] = v.w;
    }
    #pragma unroll
    for (int u = 0; u < 4; u++){            // W[c][k] -> wsT[k][c]
      float4 v = *(const float4*)&W[(c0 + row)*INF_ + k0 + kc + 4*u];
      wsT[kc + 4*u + 0][row] = v.x;
      wsT[kc + 4*u + 1][row] = v.y;
      wsT[kc + 4*u + 2][row] = v.z;
      wsT[kc + 4*u + 3][row] = v.w;
    }
    __syncthreads();
    #pragma unroll 8
    for (int k = 0; k < 64; k++){
      float4 hv = *(const float4*)&hsT[k][ty*4];
      float4 wv = *(const float4*)&wsT[k][tx*4];
      float ha[4] = {hv.x, hv.y, hv.z, hv.w};
      float wa[4] = {wv.x, wv.y, wv.z, wv.w};
      #pragma unroll
      for (int a_ = 0; a_ < 4; a_++)
        #pragma unroll
        for (int b_ = 0; b_ < 4; b_++)
          acc[a_][b_] = fmaf(ha[a_], wa[b_], acc[a_][b_]);
    }
    __syncthreads();
  }

  // scores (log2e-scaled)
  float alv[4], arv[4];
  #pragma unroll
  for (int j = 0; j < 4; j++){ alv[j] = aw[tx*4 + j]; arv[j] = aw[64 + tx*4 + j]; }
  float rmax = -3.4e38f;
  #pragma unroll
  for (int qi = 0; qi < 4; qi++){
    int r = r0 + ty*4 + qi;
    float slp = 0.f, srp = 0.f;
    #pragma unroll
    for (int j = 0; j < 4; j++){
      slp = fmaf(acc[qi][j], alv[j], slp);
      srp = fmaf(acc[qi][j], arv[j], srp);
    }
    #pragma unroll
    for (int m = 1; m < 16; m <<= 1){
      slp += __shfl_xor(slp, m, 64);
      srp += __shfl_xor(srp, m, 64);
    }
    if (tx == 0){
      slT2[(size_t)cb*NN + r] = slp * L2E;
      srT2[(size_t)cb*NN + r] = srp * L2E;
      rmax = fmaxf(rmax, srp * L2E);
    }
  }
  if (tx == 0) smax_l[ty] = rmax;

  // transpose acc -> gT (bf16) via LDS reuse
  float* T = (float*)hsT;                    // [c][r] stride 65
  #pragma unroll
  for (int qi = 0; qi < 4; qi++)
    #pragma unroll
    for (int j = 0; j < 4; j++)
      T[(tx*4 + j)*65 + ty*4 + qi] = acc[qi][j];
  __syncthreads();
  if (t == 0){
    float m = smax_l[0];
    #pragma unroll
    for (int i = 1; i < 16; i++) m = fmaxf(m, smax_l[i]);
    atomicMax(srmax2 + cb, ford(m));
  }
  int c = t >> 2, rb = (t & 3) * 16;
  ushort u16[16];
  #pragma unroll
  for (int v = 0; v < 16; v++) u16[v] = bf16u(T[c*65 + rb + v]);
  *(uint4*)&gT[(size_t)(c0 + c)*NN + r0 + rb]     = *(uint4*)&u16[0];
  *(uint4*)&gT[(size_t)(c0 + c)*NN + r0 + rb + 8] = *(uint4*)&u16[8];
}

// ---- fused masked-softmax attention via MFMA, weights built in A-frag layout ----
__launch_bounds__(256, 2)
__global__ void k_attn(const short* __restrict__ gT, const float* __restrict__ slT2,
                       const float* __restrict__ srT2, const uint32_t* __restrict__ srmax2,
                       const int* __restrict__ adj,
                       __hip_bfloat16* __restrict__ num_p, float* __restrict__ den_p){
  int t  = threadIdx.x;
  int h  = t >> 6, l = t & 63;
  int lr = l & 15, lg = l >> 4;        // row-in-tile, k-group
  int i0 = blockIdx.x * BI;
  int jb = blockIdx.y * (NN / JSPLIT); // 512 j per block
  int js = blockIdx.y;

  float srmaxh = funord(srmax2[h]);
  float slv2[4], msh2[4];
  #pragma unroll
  for (int m = 0; m < 4; m++){
    slv2[m] = slT2[(size_t)h*NN + i0 + m*16 + lr];
    float x = slv2[m] + srmaxh;
    msh2[m] = fmaxf(x, NEG * x);
  }
  f32x4 acc[4][4] = {};
  float denp[4] = {0.f, 0.f, 0.f, 0.f};
  const float* srh = srT2 + (size_t)h*NN;
  const short* gTh = gT + (size_t)h*HID*NN;

  for (int k0 = jb; k0 < jb + NN/JSPLIT; k0 += 32){
    int kk = k0 + lg*8;
    float4 s0 = *(const float4*)(srh + kk);
    float4 s1 = *(const float4*)(srh + kk + 4);
    float sr8[8] = {s0.x, s0.y, s0.z, s0.w, s1.x, s1.y, s1.z, s1.w};

    bf16x8 B[4];
    #pragma unroll
    for (int n = 0; n < 4; n++)
      B[n] = *(const bf16x8*)(gTh + (size_t)(n*16 + lr)*NN + kk);

    bf16x8 A[4];
    #pragma unroll
    for (int m = 0; m < 4; m++){
      const int* ap = adj + (size_t)(i0 + m*16 + lr)*NN + kk;
      int4 a0 = *(const int4*)ap;
      int4 a1 = *(const int4*)(ap + 4);
      int av[8] = {a0.x, a0.y, a0.z, a0.w, a1.x, a1.y, a1.z, a1.w};
      ushort u16[8];
      #pragma unroll
      for (int q = 0; q < 8; q++){
        float x  = slv2[m] + sr8[q];
        float e2 = fmaxf(x, NEG * x);
        float wv = __builtin_amdgcn_exp2f(e2 - msh2[m]);
        wv = av[q] ? wv : 0.f;
        denp[m] += wv;
        u16[q] = bf16u(wv);
      }
      A[m] = *(bf16x8*)&u16[0];
    }

    #pragma unroll
    for (int m = 0; m < 4; m++)
      #pragma unroll
      for (int n = 0; n < 4; n++)
        acc[m][n] = __builtin_amdgcn_mfma_f32_16x16x32_bf16(A[m], B[n], acc[m][n], 0, 0, 0);
  }

  // num partials (bf16): row = i0+m*16+lg*4+r, col = h*64+n*16+lr
  #pragma unroll
  for (int m = 0; m < 4; m++)
    #pragma unroll
    for (int n = 0; n < 4; n++)
      #pragma unroll
      for (int r = 0; r < 4; r++)
        num_p[((size_t)js*NN + i0 + m*16 + lg*4 + r)*OUTC + h*HID + n*16 + lr] =
            __float2bfloat16(acc[m][n][r]);

  #pragma unroll
  for (int m = 0; m < 4; m++){
    denp[m] += __shfl_xor(denp[m], 16, 64);
    denp[m] += __shfl_xor(denp[m], 32, 64);
  }
  if (lg == 0)
    #pragma unroll
    for (int m = 0; m < 4; m++)
      den_p[((size_t)js*4 + h)*NN + i0 + m*16 + lr] = denp[m];
}

// ---- combine partials: out = sum(num)/sum(den) ----
__global__ void k_comb(const __hip_bfloat16* __restrict__ num_p,
                       const float* __restrict__ den_p, float* __restrict__ out){
  int r = blockIdx.x, c = threadIdx.x;
  int h = c >> 6;
  float s = 0.f, d = 0.f;
  #pragma unroll
  for (int js = 0; js < JSPLIT; js++)
    s += __bfloat162float(num_p[((size_t)js*NN + r)*OUTC + c]);
  #pragma unroll
  for (int js = 0; js < JSPLIT; js++)
    d += den_p[((size_t)js*4 + h)*NN + r];
  out[(size_t)r*OUTC + c] = s / d;
}

extern "C" void kernel_launch(void* const* d_in, const int* in_sizes, int n_in,
                              void* d_out, int out_size, void* d_ws, size_t ws_size,
                              hipStream_t stream){
  const float* hmat = (const float*)d_in[0];
  const int*   adj  = (const int*)d_in[1];     // int32 layout confirmed in r1
  const float* W    = (const float*)d_in[2];
  const float* aw   = (const float*)d_in[3];
  float* out = (float*)d_out;
  char*  ws  = (char*)d_ws;

  // ws layout (bytes), total ~18.6 MB
  uint32_t* srmax2 = (uint32_t*)(ws);                    // 64 B
  float*    slT2   = (float*)(ws + 1024);                // 64 KB   [4][4096]
  float*    srT2   = (float*)(ws + 66560);               // 64 KB   [4][4096]
  short*    gT     = (short*)(ws + 132096);              // 2 MB    [256][4096] bf16
  float*    den_p  = (float*)(ws + 2229248);             // 512 KB  [8][4][4096]
  __hip_bfloat16* num_p = (__hip_bfloat16*)(ws + 2753536); // 16.75 MB [8][4096][256]

  hipMemsetAsync(ws, 0, 64, stream);   // srmax2 init (0 < ford(any float))
  hipLaunchKernelGGL(k_gemm, dim3(64, 4), dim3(256), 0, stream,
                     hmat, W, aw, gT, slT2, srT2, srmax2);
  hipLaunchKernelGGL(k_attn, dim3(NN/BI, JSPLIT), dim3(256), 0, stream,
                     gT, slT2, srT2, srmax2, adj, num_p, den_p);
  hipLaunchKernelGGL(k_comb, dim3(NN), dim3(256), 0, stream, num_p, den_p, out);
}